// Round 12
// baseline (159.168 us; speedup 1.0000x reference)
//
#include <hip/hip_runtime.h>
#include <cstdint>

// FlashAttention fused block: q/k/v proj -> causal attn -> out proj
// B=2, N=2048, DIM=1024, H=16, Dh=64. All compute bf16 MFMA + fp32 accum.
// R12: (1) attn zero-register K prefetch: next tile's K loads issued right
// after the QK MFMAs consume the current kc (WAR-safe in-order) -> softmax/
// pack/PV cover the L2 latency. (2) cvt + 3 weight transposes fused into one
// prep kernel (1 launch instead of 4).

typedef __bf16 bf16_t;
typedef __bf16 bf16x8 __attribute__((ext_vector_type(8)));
typedef __bf16 bf16x4 __attribute__((ext_vector_type(4)));
typedef float  f32x4  __attribute__((ext_vector_type(4)));
typedef float  f32x16 __attribute__((ext_vector_type(16)));
typedef unsigned int u32;

#define QSCALE 0.18033688011112042f  /* 0.125 * log2(e) */

// Fragment-major layouts (per bh, 131072 elems = 2048x64):
//  K/Q: elem = bh*131072 + ((q>>6)*8 + (d>>4)*2 + ((q>>5)&1))*512
//             + (((d>>3)&1)*32 + (q&31))*8 + (d&7)
//  V^T: elem = bh*131072 + ((j>>6)*8 + ((j&63)>>4)*2 + (d>>5))*512
//             + (((j>>3)&1)*32 + (d&31))*8 + (j&7)

__device__ __forceinline__ float fast_exp2(float x) {
#if __has_builtin(__builtin_amdgcn_exp2f)
  return __builtin_amdgcn_exp2f(x);
#else
  return exp2f(x);
#endif
}

// Exchange: a' = a.lo || b.lo ; b' = a.hi || b.hi (halves = lane groups 0-31/32-63)
__device__ __forceinline__ void swap32(u32& a, u32& b) {
#if __has_builtin(__builtin_amdgcn_permlane32_swap)
  typedef unsigned int u32x2 __attribute__((ext_vector_type(2)));
  const u32x2 r = __builtin_amdgcn_permlane32_swap(a, b, false, false);
  a = r[0]; b = r[1];
#else
  const u32 xa = (u32)__shfl_xor((int)a, 32, 64);
  const u32 xb = (u32)__shfl_xor((int)b, 32, 64);
  const bool hi = (threadIdx.x & 32) != 0;
  const u32 r0 = hi ? xb : a;
  const u32 r1 = hi ? b : xa;
  a = r0; b = r1;
#endif
}

// global -> LDS direct DMA, 16B per lane. LDS dest must be uniform-base + lane*16.
__device__ __forceinline__ void gload_lds16(const void* gsrc, void* ldst) {
  __builtin_amdgcn_global_load_lds(
      (__attribute__((address_space(1))) void*)(uintptr_t)gsrc,
      (__attribute__((address_space(3))) void*)(uintptr_t)(uint32_t)(uintptr_t)ldst,
      16, 0, 0);
}

__device__ __forceinline__ u32 pkbf(float a, float b) {
  const u32 lo = (u32)__builtin_bit_cast(unsigned short, (bf16_t)a);
  const u32 hi = (u32)__builtin_bit_cast(unsigned short, (bf16_t)b);
  return (hi << 16) | lo;
}

// ---------------- fused prep: x->bf16 cvt + 3 weight transposes ----------------
// blocks 0..4095: cvt (4M floats). blocks 4096..8191: 32x32 transpose tiles
// (Wq 1024, Wkv 2048, Wo 1024). Branch is block-uniform -> barrier safe.
__global__ __launch_bounds__(256) void prep_kernel(
    const float* __restrict__ x, const float* __restrict__ Wq,
    const float* __restrict__ Wkv, const float* __restrict__ Wo,
    bf16_t* __restrict__ Xbf, bf16_t* __restrict__ Wqkvt,
    bf16_t* __restrict__ Wot) {
  const int bid = blockIdx.x;
  if (bid < 4096) {
    const int idx = (bid * 256 + threadIdx.x) * 4;
    const float4 v = *(const float4*)(x + idx);
    bf16x4 o;
    o[0] = (bf16_t)v.x; o[1] = (bf16_t)v.y; o[2] = (bf16_t)v.z; o[3] = (bf16_t)v.w;
    *(bf16x4*)(Xbf + idx) = o;
  } else {
    const int tb = bid - 4096;
    const float* W; bf16_t* Wt; int Nn, bx, by;
    if (tb < 1024)      { W = Wq;  Wt = Wqkvt;                Nn = 1024; bx = tb & 31; by = tb >> 5; }
    else if (tb < 3072) { const int u = tb - 1024;
                          W = Wkv; Wt = Wqkvt + 1024 * 1024;  Nn = 2048; bx = u & 63;  by = u >> 6; }
    else                { const int u = tb - 3072;
                          W = Wo;  Wt = Wot;                  Nn = 1024; bx = u & 31;  by = u >> 5; }
    __shared__ float tile[32][33];
    const int tx = threadIdx.x & 31, ty = threadIdx.x >> 5;
    const int xcol = bx * 32 + tx;
    #pragma unroll
    for (int r0 = 0; r0 < 32; r0 += 8) {
      const int r = r0 + ty;
      tile[r][tx] = W[(size_t)(by * 32 + r) * Nn + xcol];
    }
    __syncthreads();
    const int xo = by * 32 + tx;
    #pragma unroll
    for (int r0 = 0; r0 < 32; r0 += 8) {
      const int r = r0 + ty;
      Wt[(size_t)(bx * 32 + r) * 1024 + xo] = (bf16_t)tile[tx][r];
    }
  }
}

// ---------------- GEMM: C[M][Nn] = A[M][1024] @ Bt[Nn][1024]^T ----------------
// 128xBN tile, BK=64, 4 waves (2x2 of 64x(BN/2)), 16x16x32 bf16 MFMA.
// LDS chunk swizzle: physical chunk c holds logical chunk c ^ (row&7).
// 2-phase double-buffer: prefetch next K-tile, counted vmcnt.
// MODE 1 (BN=128): fused QKV. ci<2048 -> Q/K frag-major via LDS-staged
//   coalesced epilogue (Q scaled); >=2048 -> V^T frag-major vector stores.
// MODE 2: outf = fp32 row-major [M][1024]
template <int MODE, int BN>
__global__ __launch_bounds__(256) void gemm_kernel(
    const bf16_t* __restrict__ A, const bf16_t* __restrict__ Bt,
    bf16_t* __restrict__ outQ, bf16_t* __restrict__ outK,
    bf16_t* __restrict__ outV, float* __restrict__ outf) {
  constexpr int KD = 1024;
  constexpr int NB = BN / 32;   // B-stage iters per thread
  constexpr int NW = BN / 2;    // wave col span
  constexpr int NACC = NW / 16; // acc cols per wave
  __shared__ bf16_t As[2][128][64];
  __shared__ bf16_t Bs[2][BN][64];
  const int t = threadIdx.x;
  const int lane = t & 63, w = t >> 6;
  const int wr = w >> 1, wc = w & 1;
  const int lrow = lane & 15, lq = lane >> 4;
  const int bm = blockIdx.y * 128, bn = blockIdx.x * BN;

  f32x4 acc[4][NACC] = {};

  auto stage = [&](int buf, int k0) {
    #pragma unroll
    for (int i = 0; i < 4; ++i) {
      const int lin = i * 256 + t;
      const int row = lin >> 3;
      const int sc = (lin & 7) ^ (row & 7);
      gload_lds16(A + (size_t)(bm + row) * KD + k0 + sc * 8,
                  &As[buf][0][0] + lin * 8);
    }
    #pragma unroll
    for (int i = 0; i < NB; ++i) {
      const int lin = i * 256 + t;
      const int row = lin >> 3;
      const int sc = (lin & 7) ^ (row & 7);
      gload_lds16(Bt + (size_t)(bn + row) * KD + k0 + sc * 8,
                  &Bs[buf][0][0] + lin * 8);
    }
  };

  stage(0, 0);
  for (int kt = 0; kt < KD / 64; ++kt) {
    const int cur = kt & 1;
    if (kt + 1 < KD / 64) {
      stage(cur ^ 1, (kt + 1) * 64);
      if constexpr (BN == 128)
        asm volatile("s_waitcnt vmcnt(8)" ::: "memory");
      else
        asm volatile("s_waitcnt vmcnt(6)" ::: "memory");
    } else {
      asm volatile("s_waitcnt vmcnt(0)" ::: "memory");
    }
    __builtin_amdgcn_s_barrier();

    #pragma unroll
    for (int kk = 0; kk < 2; ++kk) {
      bf16x8 aF[4], bF[NACC];
      #pragma unroll
      for (int m = 0; m < 4; ++m) {
        const int row = wr * 64 + m * 16 + lrow;
        const int ch = (kk * 4 + lq) ^ (row & 7);
        aF[m] = *(const bf16x8*)&As[cur][row][ch * 8];
      }
      #pragma unroll
      for (int n = 0; n < NACC; ++n) {
        const int row = wc * NW + n * 16 + lrow;
        const int ch = (kk * 4 + lq) ^ (row & 7);
        bF[n] = *(const bf16x8*)&Bs[cur][row][ch * 8];
      }
      #pragma unroll
      for (int m = 0; m < 4; ++m)
        #pragma unroll
        for (int n = 0; n < NACC; ++n)
          acc[m][n] = __builtin_amdgcn_mfma_f32_16x16x32_bf16(aF[m], bF[n],
                                                              acc[m][n], 0, 0, 0);
    }
    asm volatile("s_waitcnt lgkmcnt(0)" ::: "memory");
    __builtin_amdgcn_s_barrier();
  }

  if constexpr (MODE == 2) {
    #pragma unroll
    for (int m = 0; m < 4; ++m) {
      const int ri = bm + wr * 64 + m * 16 + lq * 4;
      #pragma unroll
      for (int n = 0; n < NACC; ++n) {
        const int ci = bn + wc * NW + n * 16 + lrow;
        const f32x4 v = acc[m][n];
        #pragma unroll
        for (int r = 0; r < 4; ++r)
          outf[(size_t)(ri + r) * 1024 + ci] = v[r];
      }
    }
  } else if (bn < 2048) {
    // ---- Q/K band: LDS-staged frag-major epilogue, coalesced 16B stores ----
    bf16_t* Cs = (bf16_t*)&As[0][0][0];  // 32 KB, exact fit for 128x128 bf16
    bf16_t* dst = (bn < 1024) ? outQ : outK;
    const float sc = (bn < 1024) ? QSCALE : 1.0f;
    #pragma unroll
    for (int m = 0; m < 4; ++m) {
      const int rr0 = wr * 64 + m * 16 + lq * 4;  // relative row (q) base
      #pragma unroll
      for (int n = 0; n < NACC; ++n) {
        const int c = wc * NW + n * 16 + lrow;    // relative col 0..127
        const int hh = c >> 6, d = c & 63;
        const f32x4 v = acc[m][n];
        #pragma unroll
        for (int r = 0; r < 4; ++r) {
          const int rr = rr0 + r;
          const int off = ((hh * 2 + (rr >> 6)) << 12)
                        + (((d >> 4) * 2 + ((rr >> 5) & 1)) << 9)
                        + ((((d >> 3) & 1) * 32 + (rr & 31)) << 3) + (d & 7);
          Cs[off] = (bf16_t)(v[r] * sc);
        }
      }
    }
    __syncthreads();
    const int b = bm >> 11;
    const int qc0 = (bm & 2047) >> 6;
    const int h0 = (bn & 1023) >> 6;
    #pragma unroll
    for (int chk = 0; chk < 4; ++chk) {
      const int hh = chk >> 1, qc = chk & 1;
      bf16_t* gb = dst + (size_t)(b * 16 + h0 + hh) * 131072
                 + (size_t)(qc0 + qc) * 4096;
      #pragma unroll
      for (int it = 0; it < 2; ++it) {
        const int e = (it * 256 + t) * 8;
        *(bf16x8*)(gb + e) = *(const bf16x8*)(Cs + chk * 4096 + e);
      }
    }
  } else {
    // ---- V^T band: frag-major, 4 consecutive j -> 8B vector store ----
    #pragma unroll
    for (int m = 0; m < 4; ++m) {
      const int ri = bm + wr * 64 + m * 16 + lq * 4;
      #pragma unroll
      for (int n = 0; n < NACC; ++n) {
        const int ci = bn + wc * NW + n * 16 + lrow;
        const f32x4 v = acc[m][n];
        const int hd = ci - 2048;
        const int h = hd >> 6, d = hd & 63;
        const int b = ri >> 11, j0 = ri & 2047;
        bf16x4 pk;
        pk[0] = (bf16_t)v[0]; pk[1] = (bf16_t)v[1];
        pk[2] = (bf16_t)v[2]; pk[3] = (bf16_t)v[3];
        const size_t elem = (size_t)(b * 16 + h) * 131072
            + (size_t)((j0 >> 6) * 8 + ((j0 & 63) >> 4) * 2 + (d >> 5)) * 512
            + ((((j0 >> 3) & 1) * 32) + (d & 31)) * 8 + (j0 & 7);
        *(bf16x4*)(outV + elem) = pk;
      }
    }
  }
}

// ---------------- flash attention (strip-paired, proportional wave split) ----
// grid: 1024 blocks x 256 thr (4 waves), all co-resident (4 blocks/CU,
// 4 waves/SIMD at 128-VGPR budget). Logical G = (bid&7)*128 + bid>>3 (XCD
// chunking: 4 bh per XCD -> K/V L2-resident). bh = G>>5, p = G&31.
// Strip A = 63-p (long) gets wA waves (2 or 3, proportional), strip B = p
// gets 4-wA. Per-strip KV-split with stride ws; K prefetched one tile ahead
// by code motion (loads issued right after QK MFMAs consume kc -> WAR-safe,
// zero extra registers); defer-max; per-lane half-row l; permlane32_swap P
// exchange; per-strip LDS merge, leaders write output.
__global__ void __attribute__((amdgpu_flat_work_group_size(256, 256),
                               amdgpu_waves_per_eu(4, 4)))
attn_kernel(
    const bf16_t* __restrict__ Qf, const bf16_t* __restrict__ Kf,
    const bf16_t* __restrict__ Vf, bf16_t* __restrict__ Ow) {
  const int t = threadIdx.x;
  const int lane = t & 63, w = t >> 6;
  const int l31 = lane & 31, hi = lane >> 5;
  const int G = ((blockIdx.x & 7) << 7) + (blockIdx.x >> 3);
  const int bh = G >> 5;
  const int p = G & 31;
  const int qsA = 63 - p, qsB = p;
  const int ntA = (qsA >> 1) + 1, ntB = (qsB >> 1) + 1;
  const int wA = min(3, (4 * ntA + ((ntA + ntB) >> 1)) / (ntA + ntB));
  const bool isA = (w < wA);
  const int qs = isA ? qsA : qsB;
  const int nt = isA ? ntA : ntB;
  const int widx = isA ? w : (w - wA);
  const int ws = isA ? wA : (4 - wA);
  const int qg = qs * 32 + l31;               // this lane's q row
  const bf16_t* Qb = Qf + (size_t)bh * 131072 + (size_t)(qs >> 1) * 4096 + (qs & 1) * 512;
  const bf16_t* Kb = Kf + (size_t)bh * 131072;
  const bf16_t* Vb = Vf + (size_t)bh * 131072;

  // Q frags (B-operand): row=q=l31, k = ks*16 + hi*8 + e
  bf16x8 qf[4];
  #pragma unroll
  for (int ks = 0; ks < 4; ++ks)
    qf[ks] = *(const bf16x8*)(Qb + ks * 1024 + lane * 8);

  f32x16 acc0 = {}, acc1 = {};  // O^T: col=q=l31, d = 32*t + 8*(r>>2) + 4*hi + (r&3)
  float m_run = -1e30f, l_half = 0.f;  // l_half: this lane's 32-j partial sum

  bf16x8 kc[8];
  if (widx < nt) {
    const bf16_t* K0 = Kb + (size_t)widx * 4096;
    #pragma unroll
    for (int f = 0; f < 8; ++f)
      kc[f] = *(const bf16x8*)(K0 + f * 512 + lane * 8);
  }

  for (int jt = widx; jt < nt; jt += ws) {
    const bf16_t* Vt = Vb + (size_t)jt * 4096;

    // ---- S^T = mfma(K, Q): col=q=l31, j_loc=(r&3)+8*(r>>2)+4hi ----
    f32x16 st0 = {}, st1 = {};
    #pragma unroll
    for (int ks = 0; ks < 4; ++ks) {
      st0 = __builtin_amdgcn_mfma_f32_32x32x16_bf16(kc[2 * ks], qf[ks], st0, 0, 0, 0);
      st1 = __builtin_amdgcn_mfma_f32_32x32x16_bf16(kc[2 * ks + 1], qf[ks], st1, 0, 0, 0);
    }

    // ---- prefetch next K tile into kc (WAR-safe: MFMAs above consumed kc
    // at issue; softmax/pack/PV below cover the L2 latency) ----
    const int jn = jt + ws;
    if (jn < nt) {
      const bf16_t* Kn = Kb + (size_t)jn * 4096;
      #pragma unroll
      for (int f = 0; f < 8; ++f)
        kc[f] = *(const bf16x8*)(Kn + f * 512 + lane * 8);
    }

    // ---- causal mask (only the diagonal tile) ----
    if (jt == nt - 1) {
      const int thr = qg - jt * 64;  // mask where j_loc > thr
      #pragma unroll
      for (int r = 0; r < 16; ++r) {
        const int jl = (r & 3) + 8 * (r >> 2) + 4 * hi;
        st0[r] = (jl > thr) ? -1e30f : st0[r];
        st1[r] = (32 + jl > thr) ? -1e30f : st1[r];
      }
    }

    // ---- per-lane partial max over own 32 values ----
    float t8[8];
    #pragma unroll
    for (int i = 0; i < 8; ++i)
      t8[i] = fmaxf(fmaxf(st0[i], st0[i + 8]), fmaxf(st1[i], st1[i + 8]));
    #pragma unroll
    for (int i = 0; i < 4; ++i) t8[i] = fmaxf(t8[i], t8[i + 4]);
    const float pmax = fmaxf(fmaxf(t8[0], t8[1]), fmaxf(t8[2], t8[3]));

    // ---- defer-max (T13): rescale only when some row grew > threshold ----
    if (!__all(pmax <= m_run + 8.0f)) {
      const float mx = fmaxf(pmax, __shfl_xor(pmax, 32, 64));
      const float m_new = fmaxf(m_run, mx);
      const float corr = fast_exp2(m_run - m_new);
      m_run = m_new;
      l_half *= corr;
      #pragma unroll
      for (int r = 0; r < 16; ++r) { acc0[r] *= corr; acc1[r] *= corr; }
    }

    // ---- exp + per-lane partial sum (no cross-half shuffle) ----
    #pragma unroll
    for (int r = 0; r < 16; ++r) {
      st0[r] = fast_exp2(st0[r] - m_run);
      st1[r] = fast_exp2(st1[r] - m_run);
    }
    float s8[8];
    #pragma unroll
    for (int i = 0; i < 8; ++i)
      s8[i] = (st0[i] + st0[i + 8]) + (st1[i] + st1[i + 8]);
    #pragma unroll
    for (int i = 0; i < 4; ++i) s8[i] += s8[i + 4];
    l_half += (s8[0] + s8[1]) + (s8[2] + s8[3]);

    // ---- V frags issued here (st dying; pack below covers L2 latency) ----
    bf16x8 vf[8];
    #pragma unroll
    for (int f = 0; f < 8; ++f)
      vf[f] = *(const bf16x8*)(Vt + f * 512 + lane * 8);

    // ---- P -> bf16 B-operand frags: pack pairs, permlane32_swap regroup ----
    u32 Wa[8], Wb[8];
    #pragma unroll
    for (int g = 0; g < 8; ++g) {
      Wa[g] = pkbf(st0[2 * g], st0[2 * g + 1]);
      Wb[g] = pkbf(st1[2 * g], st1[2 * g + 1]);
    }
    swap32(Wa[0], Wa[2]); swap32(Wa[1], Wa[3]);
    swap32(Wa[4], Wa[6]); swap32(Wa[5], Wa[7]);
    swap32(Wb[0], Wb[2]); swap32(Wb[1], Wb[3]);
    swap32(Wb[4], Wb[6]); swap32(Wb[5], Wb[7]);
    const uint4 u0 = make_uint4(Wa[0], Wa[1], Wa[2], Wa[3]);
    const uint4 u1 = make_uint4(Wa[4], Wa[5], Wa[6], Wa[7]);
    const uint4 u2 = make_uint4(Wb[0], Wb[1], Wb[2], Wb[3]);
    const uint4 u3 = make_uint4(Wb[4], Wb[5], Wb[6], Wb[7]);
    const bf16x8 pf0 = __builtin_bit_cast(bf16x8, u0);
    const bf16x8 pf1 = __builtin_bit_cast(bf16x8, u1);
    const bf16x8 pf2 = __builtin_bit_cast(bf16x8, u2);
    const bf16x8 pf3 = __builtin_bit_cast(bf16x8, u3);

    // ---- O^T += mfma(V, P) ----
    #pragma unroll
    for (int tt = 0; tt < 4; ++tt) {
      const bf16x8 pf = tt == 0 ? pf0 : tt == 1 ? pf1 : tt == 2 ? pf2 : pf3;
      acc0 = __builtin_amdgcn_mfma_f32_32x32x16_bf16(vf[2 * tt], pf, acc0, 0, 0, 0);
      acc1 = __builtin_amdgcn_mfma_f32_32x32x16_bf16(vf[2 * tt + 1], pf, acc1, 0, 0, 0);
    }
  }

  // ---- combine the two half-lane l partials within the wave ----
  const float l_wave = l_half + __shfl_xor(l_half, 32, 64);

  // ---- cross-wave merge via LDS: per-strip, non-leaders -> leader ----
  __shared__ float mO[2][32][64];
  __shared__ float mML[2][2][64];
  const bool leader = (w == 0) || (w == wA);
  if (!leader) {
    const int slot = isA ? (w - 1) : (wA - 1 + (w - wA - 1));
    mML[0][slot][lane] = m_run;
    mML[1][slot][lane] = l_wave;
    #pragma unroll
    for (int r = 0; r < 16; ++r) {
      mO[slot][r][lane] = acc0[r];
      mO[slot][16 + r][lane] = acc1[r];
    }
  }
  __syncthreads();
  if (leader) {
    const int base = isA ? 0 : (wA - 1);
    const int nsl = ws - 1;  // 0..2 partials to merge
    float mk[2], lk[2], ck[2];
    float mt = m_run;
    for (int k = 0; k < nsl; ++k) {
      mk[k] = mML[0][base + k][lane];
      lk[k] = mML[1][base + k][lane];
      mt = fmaxf(mt, mk[k]);
    }
    const float c0 = fast_exp2(m_run - mt);
    float l = l_wave * c0;
    for (int k = 0; k < nsl; ++k) {
      ck[k] = fast_exp2(mk[k] - mt);
      l += lk[k] * ck[k];
    }
    const float inv = 1.0f / l;
    const int b = bh >> 4, h = bh & 15;
    bf16_t* Obase = Ow + (((size_t)(b * 2048 + qg)) << 10) + h * 64;
    #pragma unroll
    for (int g = 0; g < 4; ++g) {
      bf16x4 p0, p1;
      #pragma unroll
      for (int j = 0; j < 4; ++j) {
        float a0 = acc0[4 * g + j] * c0;
        float a1 = acc1[4 * g + j] * c0;
        for (int k = 0; k < nsl; ++k) {
          a0 += mO[base + k][4 * g + j][lane] * ck[k];
          a1 += mO[base + k][16 + 4 * g + j][lane] * ck[k];
        }
        p0[j] = (bf16_t)(a0 * inv);
        p1[j] = (bf16_t)(a1 * inv);
      }
      *(bf16x4*)(Obase + 8 * g + 4 * hi) = p0;
      *(bf16x4*)(Obase + 32 + 8 * g + 4 * hi) = p1;
    }
  }
}

// ---------------- orchestration ----------------
extern "C" void kernel_launch(void* const* d_in, const int* in_sizes, int n_in,
                              void* d_out, int out_size, void* d_ws, size_t ws_size,
                              hipStream_t stream) {
  const float* x   = (const float*)d_in[0];
  const float* Wq  = (const float*)d_in[1];
  const float* Wkv = (const float*)d_in[2];
  const float* Wo  = (const float*)d_in[3];
  float* out = (float*)d_out;
  char* ws = (char*)d_ws;

  const size_t MB = 1024 * 1024;
  bf16_t* Xbf   = (bf16_t*)(ws);             // [4096][1024]       8 MiB
  bf16_t* Wqkvt = (bf16_t*)(ws + 8 * MB);    // [3072][1024]       6 MiB
  bf16_t* Wot   = (bf16_t*)(ws + 14 * MB);   // [1024][1024]       2 MiB
  bf16_t* Qw    = (bf16_t*)(ws + 16 * MB);   // frag-major Q       8 MiB (pre-scaled)
  bf16_t* Kw    = (bf16_t*)(ws + 24 * MB);   // frag-major K       8 MiB
  bf16_t* Vtw   = (bf16_t*)(ws + 32 * MB);   // frag-major V^T     8 MiB
  bf16_t* Aw    = (bf16_t*)(ws + 40 * MB);   // [4096][1024]       8 MiB

  prep_kernel<<<8192, 256, 0, stream>>>(x, Wq, Wkv, Wo, Xbf, Wqkvt, Wot);
  gemm_kernel<1, 128><<<dim3(24, 32), 256, 0, stream>>>(Xbf, Wqkvt, Qw, Kw, Vtw, nullptr);
  attn_kernel<<<1024, 256, 0, stream>>>(Qw, Kw, Vtw, Aw);
  gemm_kernel<2, 64><<<dim3(16, 32), 256, 0, stream>>>(Aw, Wot, nullptr, nullptr, nullptr, out);
}

// Round 13
// 96.669 us; speedup vs baseline: 1.6465x; 1.6465x over previous
//
#include <hip/hip_runtime.h>
#include <cstdint>

// FlashAttention fused block: q/k/v proj -> causal attn -> out proj
// B=2, N=2048, DIM=1024, H=16, Dh=64. All compute bf16 MFMA + fp32 accum.
// R13: revert R12's attn K-prefetch (it forced ~32 extra live VGPRs under the
// pinned 4-waves/EU budget -> 283MB scratch spill). attn = R11 exactly.
// Keep R12's fused prep kernel (cvt + 3 transposes in one launch).

typedef __bf16 bf16_t;
typedef __bf16 bf16x8 __attribute__((ext_vector_type(8)));
typedef __bf16 bf16x4 __attribute__((ext_vector_type(4)));
typedef float  f32x4  __attribute__((ext_vector_type(4)));
typedef float  f32x16 __attribute__((ext_vector_type(16)));
typedef unsigned int u32;

#define QSCALE 0.18033688011112042f  /* 0.125 * log2(e) */

// Fragment-major layouts (per bh, 131072 elems = 2048x64):
//  K/Q: elem = bh*131072 + ((q>>6)*8 + (d>>4)*2 + ((q>>5)&1))*512
//             + (((d>>3)&1)*32 + (q&31))*8 + (d&7)
//  V^T: elem = bh*131072 + ((j>>6)*8 + ((j&63)>>4)*2 + (d>>5))*512
//             + (((j>>3)&1)*32 + (d&31))*8 + (j&7)

__device__ __forceinline__ float fast_exp2(float x) {
#if __has_builtin(__builtin_amdgcn_exp2f)
  return __builtin_amdgcn_exp2f(x);
#else
  return exp2f(x);
#endif
}

// Exchange: a' = a.lo || b.lo ; b' = a.hi || b.hi (halves = lane groups 0-31/32-63)
__device__ __forceinline__ void swap32(u32& a, u32& b) {
#if __has_builtin(__builtin_amdgcn_permlane32_swap)
  typedef unsigned int u32x2 __attribute__((ext_vector_type(2)));
  const u32x2 r = __builtin_amdgcn_permlane32_swap(a, b, false, false);
  a = r[0]; b = r[1];
#else
  const u32 xa = (u32)__shfl_xor((int)a, 32, 64);
  const u32 xb = (u32)__shfl_xor((int)b, 32, 64);
  const bool hi = (threadIdx.x & 32) != 0;
  const u32 r0 = hi ? xb : a;
  const u32 r1 = hi ? b : xa;
  a = r0; b = r1;
#endif
}

// global -> LDS direct DMA, 16B per lane. LDS dest must be uniform-base + lane*16.
__device__ __forceinline__ void gload_lds16(const void* gsrc, void* ldst) {
  __builtin_amdgcn_global_load_lds(
      (__attribute__((address_space(1))) void*)(uintptr_t)gsrc,
      (__attribute__((address_space(3))) void*)(uintptr_t)(uint32_t)(uintptr_t)ldst,
      16, 0, 0);
}

__device__ __forceinline__ u32 pkbf(float a, float b) {
  const u32 lo = (u32)__builtin_bit_cast(unsigned short, (bf16_t)a);
  const u32 hi = (u32)__builtin_bit_cast(unsigned short, (bf16_t)b);
  return (hi << 16) | lo;
}

// ---------------- fused prep: x->bf16 cvt + 3 weight transposes ----------------
// blocks 0..4095: cvt (4M floats). blocks 4096..8191: 32x32 transpose tiles
// (Wq 1024, Wkv 2048, Wo 1024). Branch is block-uniform -> barrier safe.
__global__ __launch_bounds__(256) void prep_kernel(
    const float* __restrict__ x, const float* __restrict__ Wq,
    const float* __restrict__ Wkv, const float* __restrict__ Wo,
    bf16_t* __restrict__ Xbf, bf16_t* __restrict__ Wqkvt,
    bf16_t* __restrict__ Wot) {
  const int bid = blockIdx.x;
  if (bid < 4096) {
    const int idx = (bid * 256 + threadIdx.x) * 4;
    const float4 v = *(const float4*)(x + idx);
    bf16x4 o;
    o[0] = (bf16_t)v.x; o[1] = (bf16_t)v.y; o[2] = (bf16_t)v.z; o[3] = (bf16_t)v.w;
    *(bf16x4*)(Xbf + idx) = o;
  } else {
    const int tb = bid - 4096;
    const float* W; bf16_t* Wt; int Nn, bx, by;
    if (tb < 1024)      { W = Wq;  Wt = Wqkvt;                Nn = 1024; bx = tb & 31; by = tb >> 5; }
    else if (tb < 3072) { const int u = tb - 1024;
                          W = Wkv; Wt = Wqkvt + 1024 * 1024;  Nn = 2048; bx = u & 63;  by = u >> 6; }
    else                { const int u = tb - 3072;
                          W = Wo;  Wt = Wot;                  Nn = 1024; bx = u & 31;  by = u >> 5; }
    __shared__ float tile[32][33];
    const int tx = threadIdx.x & 31, ty = threadIdx.x >> 5;
    const int xcol = bx * 32 + tx;
    #pragma unroll
    for (int r0 = 0; r0 < 32; r0 += 8) {
      const int r = r0 + ty;
      tile[r][tx] = W[(size_t)(by * 32 + r) * Nn + xcol];
    }
    __syncthreads();
    const int xo = by * 32 + tx;
    #pragma unroll
    for (int r0 = 0; r0 < 32; r0 += 8) {
      const int r = r0 + ty;
      Wt[(size_t)(bx * 32 + r) * 1024 + xo] = (bf16_t)tile[tx][r];
    }
  }
}

// ---------------- GEMM: C[M][Nn] = A[M][1024] @ Bt[Nn][1024]^T ----------------
// 128xBN tile, BK=64, 4 waves (2x2 of 64x(BN/2)), 16x16x32 bf16 MFMA.
// LDS chunk swizzle: physical chunk c holds logical chunk c ^ (row&7).
// 2-phase double-buffer: prefetch next K-tile, counted vmcnt.
// MODE 1 (BN=128): fused QKV. ci<2048 -> Q/K frag-major via LDS-staged
//   coalesced epilogue (Q scaled); >=2048 -> V^T frag-major vector stores.
// MODE 2: outf = fp32 row-major [M][1024]
template <int MODE, int BN>
__global__ __launch_bounds__(256) void gemm_kernel(
    const bf16_t* __restrict__ A, const bf16_t* __restrict__ Bt,
    bf16_t* __restrict__ outQ, bf16_t* __restrict__ outK,
    bf16_t* __restrict__ outV, float* __restrict__ outf) {
  constexpr int KD = 1024;
  constexpr int NB = BN / 32;   // B-stage iters per thread
  constexpr int NW = BN / 2;    // wave col span
  constexpr int NACC = NW / 16; // acc cols per wave
  __shared__ bf16_t As[2][128][64];
  __shared__ bf16_t Bs[2][BN][64];
  const int t = threadIdx.x;
  const int lane = t & 63, w = t >> 6;
  const int wr = w >> 1, wc = w & 1;
  const int lrow = lane & 15, lq = lane >> 4;
  const int bm = blockIdx.y * 128, bn = blockIdx.x * BN;

  f32x4 acc[4][NACC] = {};

  auto stage = [&](int buf, int k0) {
    #pragma unroll
    for (int i = 0; i < 4; ++i) {
      const int lin = i * 256 + t;
      const int row = lin >> 3;
      const int sc = (lin & 7) ^ (row & 7);
      gload_lds16(A + (size_t)(bm + row) * KD + k0 + sc * 8,
                  &As[buf][0][0] + lin * 8);
    }
    #pragma unroll
    for (int i = 0; i < NB; ++i) {
      const int lin = i * 256 + t;
      const int row = lin >> 3;
      const int sc = (lin & 7) ^ (row & 7);
      gload_lds16(Bt + (size_t)(bn + row) * KD + k0 + sc * 8,
                  &Bs[buf][0][0] + lin * 8);
    }
  };

  stage(0, 0);
  for (int kt = 0; kt < KD / 64; ++kt) {
    const int cur = kt & 1;
    if (kt + 1 < KD / 64) {
      stage(cur ^ 1, (kt + 1) * 64);
      if constexpr (BN == 128)
        asm volatile("s_waitcnt vmcnt(8)" ::: "memory");
      else
        asm volatile("s_waitcnt vmcnt(6)" ::: "memory");
    } else {
      asm volatile("s_waitcnt vmcnt(0)" ::: "memory");
    }
    __builtin_amdgcn_s_barrier();

    #pragma unroll
    for (int kk = 0; kk < 2; ++kk) {
      bf16x8 aF[4], bF[NACC];
      #pragma unroll
      for (int m = 0; m < 4; ++m) {
        const int row = wr * 64 + m * 16 + lrow;
        const int ch = (kk * 4 + lq) ^ (row & 7);
        aF[m] = *(const bf16x8*)&As[cur][row][ch * 8];
      }
      #pragma unroll
      for (int n = 0; n < NACC; ++n) {
        const int row = wc * NW + n * 16 + lrow;
        const int ch = (kk * 4 + lq) ^ (row & 7);
        bF[n] = *(const bf16x8*)&Bs[cur][row][ch * 8];
      }
      #pragma unroll
      for (int m = 0; m < 4; ++m)
        #pragma unroll
        for (int n = 0; n < NACC; ++n)
          acc[m][n] = __builtin_amdgcn_mfma_f32_16x16x32_bf16(aF[m], bF[n],
                                                              acc[m][n], 0, 0, 0);
    }
    asm volatile("s_waitcnt lgkmcnt(0)" ::: "memory");
    __builtin_amdgcn_s_barrier();
  }

  if constexpr (MODE == 2) {
    #pragma unroll
    for (int m = 0; m < 4; ++m) {
      const int ri = bm + wr * 64 + m * 16 + lq * 4;
      #pragma unroll
      for (int n = 0; n < NACC; ++n) {
        const int ci = bn + wc * NW + n * 16 + lrow;
        const f32x4 v = acc[m][n];
        #pragma unroll
        for (int r = 0; r < 4; ++r)
          outf[(size_t)(ri + r) * 1024 + ci] = v[r];
      }
    }
  } else if (bn < 2048) {
    // ---- Q/K band: LDS-staged frag-major epilogue, coalesced 16B stores ----
    bf16_t* Cs = (bf16_t*)&As[0][0][0];  // 32 KB, exact fit for 128x128 bf16
    bf16_t* dst = (bn < 1024) ? outQ : outK;
    const float sc = (bn < 1024) ? QSCALE : 1.0f;
    #pragma unroll
    for (int m = 0; m < 4; ++m) {
      const int rr0 = wr * 64 + m * 16 + lq * 4;  // relative row (q) base
      #pragma unroll
      for (int n = 0; n < NACC; ++n) {
        const int c = wc * NW + n * 16 + lrow;    // relative col 0..127
        const int hh = c >> 6, d = c & 63;
        const f32x4 v = acc[m][n];
        #pragma unroll
        for (int r = 0; r < 4; ++r) {
          const int rr = rr0 + r;
          const int off = ((hh * 2 + (rr >> 6)) << 12)
                        + (((d >> 4) * 2 + ((rr >> 5) & 1)) << 9)
                        + ((((d >> 3) & 1) * 32 + (rr & 31)) << 3) + (d & 7);
          Cs[off] = (bf16_t)(v[r] * sc);
        }
      }
    }
    __syncthreads();
    const int b = bm >> 11;
    const int qc0 = (bm & 2047) >> 6;
    const int h0 = (bn & 1023) >> 6;
    #pragma unroll
    for (int chk = 0; chk < 4; ++chk) {
      const int hh = chk >> 1, qc = chk & 1;
      bf16_t* gb = dst + (size_t)(b * 16 + h0 + hh) * 131072
                 + (size_t)(qc0 + qc) * 4096;
      #pragma unroll
      for (int it = 0; it < 2; ++it) {
        const int e = (it * 256 + t) * 8;
        *(bf16x8*)(gb + e) = *(const bf16x8*)(Cs + chk * 4096 + e);
      }
    }
  } else {
    // ---- V^T band: frag-major, 4 consecutive j -> 8B vector store ----
    #pragma unroll
    for (int m = 0; m < 4; ++m) {
      const int ri = bm + wr * 64 + m * 16 + lq * 4;
      #pragma unroll
      for (int n = 0; n < NACC; ++n) {
        const int ci = bn + wc * NW + n * 16 + lrow;
        const f32x4 v = acc[m][n];
        const int hd = ci - 2048;
        const int h = hd >> 6, d = hd & 63;
        const int b = ri >> 11, j0 = ri & 2047;
        bf16x4 pk;
        pk[0] = (bf16_t)v[0]; pk[1] = (bf16_t)v[1];
        pk[2] = (bf16_t)v[2]; pk[3] = (bf16_t)v[3];
        const size_t elem = (size_t)(b * 16 + h) * 131072
            + (size_t)((j0 >> 6) * 8 + ((j0 & 63) >> 4) * 2 + (d >> 5)) * 512
            + ((((j0 >> 3) & 1) * 32) + (d & 31)) * 8 + (j0 & 7);
        *(bf16x4*)(outV + elem) = pk;
      }
    }
  }
}

// ---------------- flash attention (strip-paired, proportional wave split) ----
// grid: 1024 blocks x 256 thr (4 waves), all co-resident (4 blocks/CU,
// 4 waves/SIMD at 128-VGPR budget). Logical G = (bid&7)*128 + bid>>3 (XCD
// chunking: 4 bh per XCD -> K/V L2-resident). bh = G>>5, p = G&31.
// Strip A = 63-p (long) gets wA waves (2 or 3, proportional), strip B = p
// gets 4-wA. Per-strip KV-split with stride ws; defer-max; per-lane half-row
// l; permlane32_swap P exchange; per-strip LDS merge, leaders write output.
// NOTE (R12 lesson): do NOT prefetch K across the softmax tail -- the
// register budget is exactly full; extended kc liveness spills to scratch.
__global__ void __attribute__((amdgpu_flat_work_group_size(256, 256),
                               amdgpu_waves_per_eu(4, 4)))
attn_kernel(
    const bf16_t* __restrict__ Qf, const bf16_t* __restrict__ Kf,
    const bf16_t* __restrict__ Vf, bf16_t* __restrict__ Ow) {
  const int t = threadIdx.x;
  const int lane = t & 63, w = t >> 6;
  const int l31 = lane & 31, hi = lane >> 5;
  const int G = ((blockIdx.x & 7) << 7) + (blockIdx.x >> 3);
  const int bh = G >> 5;
  const int p = G & 31;
  const int qsA = 63 - p, qsB = p;
  const int ntA = (qsA >> 1) + 1, ntB = (qsB >> 1) + 1;
  const int wA = min(3, (4 * ntA + ((ntA + ntB) >> 1)) / (ntA + ntB));
  const bool isA = (w < wA);
  const int qs = isA ? qsA : qsB;
  const int nt = isA ? ntA : ntB;
  const int widx = isA ? w : (w - wA);
  const int ws = isA ? wA : (4 - wA);
  const int qg = qs * 32 + l31;               // this lane's q row
  const bf16_t* Qb = Qf + (size_t)bh * 131072 + (size_t)(qs >> 1) * 4096 + (qs & 1) * 512;
  const bf16_t* Kb = Kf + (size_t)bh * 131072;
  const bf16_t* Vb = Vf + (size_t)bh * 131072;

  // Q frags (B-operand): row=q=l31, k = ks*16 + hi*8 + e
  bf16x8 qf[4];
  #pragma unroll
  for (int ks = 0; ks < 4; ++ks)
    qf[ks] = *(const bf16x8*)(Qb + ks * 1024 + lane * 8);

  f32x16 acc0 = {}, acc1 = {};  // O^T: col=q=l31, d = 32*t + 8*(r>>2) + 4*hi + (r&3)
  float m_run = -1e30f, l_half = 0.f;  // l_half: this lane's 32-j partial sum

  for (int jt = widx; jt < nt; jt += ws) {
    const bf16_t* Kt = Kb + (size_t)jt * 4096;
    const bf16_t* Vt = Vb + (size_t)jt * 4096;

    // ---- K frags, coalesced 1KB loads (latency hidden by co-resident waves)
    bf16x8 kc[8];
    #pragma unroll
    for (int f = 0; f < 8; ++f)
      kc[f] = *(const bf16x8*)(Kt + f * 512 + lane * 8);

    // ---- S^T = mfma(K, Q): col=q=l31, j_loc=(r&3)+8*(r>>2)+4hi ----
    f32x16 st0 = {}, st1 = {};
    #pragma unroll
    for (int ks = 0; ks < 4; ++ks) {
      st0 = __builtin_amdgcn_mfma_f32_32x32x16_bf16(kc[2 * ks], qf[ks], st0, 0, 0, 0);
      st1 = __builtin_amdgcn_mfma_f32_32x32x16_bf16(kc[2 * ks + 1], qf[ks], st1, 0, 0, 0);
    }

    // ---- causal mask (only the diagonal tile) ----
    if (jt == nt - 1) {
      const int thr = qg - jt * 64;  // mask where j_loc > thr
      #pragma unroll
      for (int r = 0; r < 16; ++r) {
        const int jl = (r & 3) + 8 * (r >> 2) + 4 * hi;
        st0[r] = (jl > thr) ? -1e30f : st0[r];
        st1[r] = (32 + jl > thr) ? -1e30f : st1[r];
      }
    }

    // ---- per-lane partial max over own 32 values ----
    float t8[8];
    #pragma unroll
    for (int i = 0; i < 8; ++i)
      t8[i] = fmaxf(fmaxf(st0[i], st0[i + 8]), fmaxf(st1[i], st1[i + 8]));
    #pragma unroll
    for (int i = 0; i < 4; ++i) t8[i] = fmaxf(t8[i], t8[i + 4]);
    const float pmax = fmaxf(fmaxf(t8[0], t8[1]), fmaxf(t8[2], t8[3]));

    // ---- defer-max (T13): rescale only when some row grew > threshold ----
    if (!__all(pmax <= m_run + 8.0f)) {
      const float mx = fmaxf(pmax, __shfl_xor(pmax, 32, 64));
      const float m_new = fmaxf(m_run, mx);
      const float corr = fast_exp2(m_run - m_new);
      m_run = m_new;
      l_half *= corr;
      #pragma unroll
      for (int r = 0; r < 16; ++r) { acc0[r] *= corr; acc1[r] *= corr; }
    }

    // ---- exp + per-lane partial sum (no cross-half shuffle) ----
    #pragma unroll
    for (int r = 0; r < 16; ++r) {
      st0[r] = fast_exp2(st0[r] - m_run);
      st1[r] = fast_exp2(st1[r] - m_run);
    }
    float s8[8];
    #pragma unroll
    for (int i = 0; i < 8; ++i)
      s8[i] = (st0[i] + st0[i + 8]) + (st1[i] + st1[i + 8]);
    #pragma unroll
    for (int i = 0; i < 4; ++i) s8[i] += s8[i + 4];
    l_half += (s8[0] + s8[1]) + (s8[2] + s8[3]);

    // ---- V frags issued here (kc/st dying; pack below covers L2 latency) ----
    bf16x8 vf[8];
    #pragma unroll
    for (int f = 0; f < 8; ++f)
      vf[f] = *(const bf16x8*)(Vt + f * 512 + lane * 8);

    // ---- P -> bf16 B-operand frags: pack pairs, permlane32_swap regroup ----
    u32 Wa[8], Wb[8];
    #pragma unroll
    for (int g = 0; g < 8; ++g) {
      Wa[g] = pkbf(st0[2 * g], st0[2 * g + 1]);
      Wb[g] = pkbf(st1[2 * g], st1[2 * g + 1]);
    }
    swap32(Wa[0], Wa[2]); swap32(Wa[1], Wa[3]);
    swap32(Wa[4], Wa[6]); swap32(Wa[5], Wa[7]);
    swap32(Wb[0], Wb[2]); swap32(Wb[1], Wb[3]);
    swap32(Wb[4], Wb[6]); swap32(Wb[5], Wb[7]);
    const uint4 u0 = make_uint4(Wa[0], Wa[1], Wa[2], Wa[3]);
    const uint4 u1 = make_uint4(Wa[4], Wa[5], Wa[6], Wa[7]);
    const uint4 u2 = make_uint4(Wb[0], Wb[1], Wb[2], Wb[3]);
    const uint4 u3 = make_uint4(Wb[4], Wb[5], Wb[6], Wb[7]);
    const bf16x8 pf0 = __builtin_bit_cast(bf16x8, u0);
    const bf16x8 pf1 = __builtin_bit_cast(bf16x8, u1);
    const bf16x8 pf2 = __builtin_bit_cast(bf16x8, u2);
    const bf16x8 pf3 = __builtin_bit_cast(bf16x8, u3);

    // ---- O^T += mfma(V, P) ----
    #pragma unroll
    for (int tt = 0; tt < 4; ++tt) {
      const bf16x8 pf = tt == 0 ? pf0 : tt == 1 ? pf1 : tt == 2 ? pf2 : pf3;
      acc0 = __builtin_amdgcn_mfma_f32_32x32x16_bf16(vf[2 * tt], pf, acc0, 0, 0, 0);
      acc1 = __builtin_amdgcn_mfma_f32_32x32x16_bf16(vf[2 * tt + 1], pf, acc1, 0, 0, 0);
    }
  }

  // ---- combine the two half-lane l partials within the wave ----
  const float l_wave = l_half + __shfl_xor(l_half, 32, 64);

  // ---- cross-wave merge via LDS: per-strip, non-leaders -> leader ----
  __shared__ float mO[2][32][64];
  __shared__ float mML[2][2][64];
  const bool leader = (w == 0) || (w == wA);
  if (!leader) {
    const int slot = isA ? (w - 1) : (wA - 1 + (w - wA - 1));
    mML[0][slot][lane] = m_run;
    mML[1][slot][lane] = l_wave;
    #pragma unroll
    for (int r = 0; r < 16; ++r) {
      mO[slot][r][lane] = acc0[r];
      mO[slot][16 + r][lane] = acc1[r];
    }
  }
  __syncthreads();
  if (leader) {
    const int base = isA ? 0 : (wA - 1);
    const int nsl = ws - 1;  // 0..2 partials to merge
    float mk[2], lk[2], ck[2];
    float mt = m_run;
    for (int k = 0; k < nsl; ++k) {
      mk[k] = mML[0][base + k][lane];
      lk[k] = mML[1][base + k][lane];
      mt = fmaxf(mt, mk[k]);
    }
    const float c0 = fast_exp2(m_run - mt);
    float l = l_wave * c0;
    for (int k = 0; k < nsl; ++k) {
      ck[k] = fast_exp2(mk[k] - mt);
      l += lk[k] * ck[k];
    }
    const float inv = 1.0f / l;
    const int b = bh >> 4, h = bh & 15;
    bf16_t* Obase = Ow + (((size_t)(b * 2048 + qg)) << 10) + h * 64;
    #pragma unroll
    for (int g = 0; g < 4; ++g) {
      bf16x4 p0, p1;
      #pragma unroll
      for (int j = 0; j < 4; ++j) {
        float a0 = acc0[4 * g + j] * c0;
        float a1 = acc1[4 * g + j] * c0;
        for (int k = 0; k < nsl; ++k) {
          a0 += mO[base + k][4 * g + j][lane] * ck[k];
          a1 += mO[base + k][16 + 4 * g + j][lane] * ck[k];
        }
        p0[j] = (bf16_t)(a0 * inv);
        p1[j] = (bf16_t)(a1 * inv);
      }
      *(bf16x4*)(Obase + 8 * g + 4 * hi) = p0;
      *(bf16x4*)(Obase + 32 + 8 * g + 4 * hi) = p1;
    }
  }
}

// ---------------- orchestration ----------------
extern "C" void kernel_launch(void* const* d_in, const int* in_sizes, int n_in,
                              void* d_out, int out_size, void* d_ws, size_t ws_size,
                              hipStream_t stream) {
  const float* x   = (const float*)d_in[0];
  const float* Wq  = (const float*)d_in[1];
  const float* Wkv = (const float*)d_in[2];
  const float* Wo  = (const float*)d_in[3];
  float* out = (float*)d_out;
  char* ws = (char*)d_ws;

  const size_t MB = 1024 * 1024;
  bf16_t* Xbf   = (bf16_t*)(ws);             // [4096][1024]       8 MiB
  bf16_t* Wqkvt = (bf16_t*)(ws + 8 * MB);    // [3072][1024]       6 MiB
  bf16_t* Wot   = (bf16_t*)(ws + 14 * MB);   // [1024][1024]       2 MiB
  bf16_t* Qw    = (bf16_t*)(ws + 16 * MB);   // frag-major Q       8 MiB (pre-scaled)
  bf16_t* Kw    = (bf16_t*)(ws + 24 * MB);   // frag-major K       8 MiB
  bf16_t* Vtw   = (bf16_t*)(ws + 32 * MB);   // frag-major V^T     8 MiB
  bf16_t* Aw    = (bf16_t*)(ws + 40 * MB);   // [4096][1024]       8 MiB

  prep_kernel<<<8192, 256, 0, stream>>>(x, Wq, Wkv, Wo, Xbf, Wqkvt, Wot);
  gemm_kernel<1, 128><<<dim3(24, 32), 256, 0, stream>>>(Xbf, Wqkvt, Qw, Kw, Vtw, nullptr);
  attn_kernel<<<1024, 256, 0, stream>>>(Qw, Kw, Vtw, Aw);
  gemm_kernel<2, 64><<<dim3(16, 32), 256, 0, stream>>>(Aw, Wot, nullptr, nullptr, nullptr, out);
}

// Round 14
// 95.654 us; speedup vs baseline: 1.6640x; 1.0106x over previous
//
#include <hip/hip_runtime.h>
#include <cstdint>

// FlashAttention fused block: q/k/v proj -> causal attn -> out proj
// B=2, N=2048, DIM=1024, H=16, Dh=64. All compute bf16 MFMA + fp32 accum.
// R14: T1 XCD-chunked blockIdx swizzle in both GEMMs (bijective, nwg%8==0):
// each XCD gets a contiguous chunk of block-rows -> A-panels fetched from HBM
// by ONE XCD instead of all 8. attn/prep frozen at R13.

typedef __bf16 bf16_t;
typedef __bf16 bf16x8 __attribute__((ext_vector_type(8)));
typedef __bf16 bf16x4 __attribute__((ext_vector_type(4)));
typedef float  f32x4  __attribute__((ext_vector_type(4)));
typedef float  f32x16 __attribute__((ext_vector_type(16)));
typedef unsigned int u32;

#define QSCALE 0.18033688011112042f  /* 0.125 * log2(e) */

// Fragment-major layouts (per bh, 131072 elems = 2048x64):
//  K/Q: elem = bh*131072 + ((q>>6)*8 + (d>>4)*2 + ((q>>5)&1))*512
//             + (((d>>3)&1)*32 + (q&31))*8 + (d&7)
//  V^T: elem = bh*131072 + ((j>>6)*8 + ((j&63)>>4)*2 + (d>>5))*512
//             + (((j>>3)&1)*32 + (d&31))*8 + (j&7)

__device__ __forceinline__ float fast_exp2(float x) {
#if __has_builtin(__builtin_amdgcn_exp2f)
  return __builtin_amdgcn_exp2f(x);
#else
  return exp2f(x);
#endif
}

// Exchange: a' = a.lo || b.lo ; b' = a.hi || b.hi (halves = lane groups 0-31/32-63)
__device__ __forceinline__ void swap32(u32& a, u32& b) {
#if __has_builtin(__builtin_amdgcn_permlane32_swap)
  typedef unsigned int u32x2 __attribute__((ext_vector_type(2)));
  const u32x2 r = __builtin_amdgcn_permlane32_swap(a, b, false, false);
  a = r[0]; b = r[1];
#else
  const u32 xa = (u32)__shfl_xor((int)a, 32, 64);
  const u32 xb = (u32)__shfl_xor((int)b, 32, 64);
  const bool hi = (threadIdx.x & 32) != 0;
  const u32 r0 = hi ? xb : a;
  const u32 r1 = hi ? b : xa;
  a = r0; b = r1;
#endif
}

// global -> LDS direct DMA, 16B per lane. LDS dest must be uniform-base + lane*16.
__device__ __forceinline__ void gload_lds16(const void* gsrc, void* ldst) {
  __builtin_amdgcn_global_load_lds(
      (__attribute__((address_space(1))) void*)(uintptr_t)gsrc,
      (__attribute__((address_space(3))) void*)(uintptr_t)(uint32_t)(uintptr_t)ldst,
      16, 0, 0);
}

__device__ __forceinline__ u32 pkbf(float a, float b) {
  const u32 lo = (u32)__builtin_bit_cast(unsigned short, (bf16_t)a);
  const u32 hi = (u32)__builtin_bit_cast(unsigned short, (bf16_t)b);
  return (hi << 16) | lo;
}

// ---------------- fused prep: x->bf16 cvt + 3 weight transposes ----------------
// blocks 0..4095: cvt (4M floats). blocks 4096..8191: 32x32 transpose tiles
// (Wq 1024, Wkv 2048, Wo 1024). Branch is block-uniform -> barrier safe.
__global__ __launch_bounds__(256) void prep_kernel(
    const float* __restrict__ x, const float* __restrict__ Wq,
    const float* __restrict__ Wkv, const float* __restrict__ Wo,
    bf16_t* __restrict__ Xbf, bf16_t* __restrict__ Wqkvt,
    bf16_t* __restrict__ Wot) {
  const int bid = blockIdx.x;
  if (bid < 4096) {
    const int idx = (bid * 256 + threadIdx.x) * 4;
    const float4 v = *(const float4*)(x + idx);
    bf16x4 o;
    o[0] = (bf16_t)v.x; o[1] = (bf16_t)v.y; o[2] = (bf16_t)v.z; o[3] = (bf16_t)v.w;
    *(bf16x4*)(Xbf + idx) = o;
  } else {
    const int tb = bid - 4096;
    const float* W; bf16_t* Wt; int Nn, bx, by;
    if (tb < 1024)      { W = Wq;  Wt = Wqkvt;                Nn = 1024; bx = tb & 31; by = tb >> 5; }
    else if (tb < 3072) { const int u = tb - 1024;
                          W = Wkv; Wt = Wqkvt + 1024 * 1024;  Nn = 2048; bx = u & 63;  by = u >> 6; }
    else                { const int u = tb - 3072;
                          W = Wo;  Wt = Wot;                  Nn = 1024; bx = u & 31;  by = u >> 5; }
    __shared__ float tile[32][33];
    const int tx = threadIdx.x & 31, ty = threadIdx.x >> 5;
    const int xcol = bx * 32 + tx;
    #pragma unroll
    for (int r0 = 0; r0 < 32; r0 += 8) {
      const int r = r0 + ty;
      tile[r][tx] = W[(size_t)(by * 32 + r) * Nn + xcol];
    }
    __syncthreads();
    const int xo = by * 32 + tx;
    #pragma unroll
    for (int r0 = 0; r0 < 32; r0 += 8) {
      const int r = r0 + ty;
      Wt[(size_t)(bx * 32 + r) * 1024 + xo] = (bf16_t)tile[tx][r];
    }
  }
}

// ---------------- GEMM: C[M][Nn] = A[M][1024] @ Bt[Nn][1024]^T ----------------
// 128xBN tile, BK=64, 4 waves (2x2 of 64x(BN/2)), 16x16x32 bf16 MFMA.
// LDS chunk swizzle: physical chunk c holds logical chunk c ^ (row&7).
// 2-phase double-buffer: prefetch next K-tile, counted vmcnt.
// T1: XCD-chunked block swizzle (bid%8 -> XCD; contiguous chunk of nwg/8).
// MODE 1 (BN=128): fused QKV. ci<2048 -> Q/K frag-major via LDS-staged
//   coalesced epilogue (Q scaled); >=2048 -> V^T frag-major vector stores.
// MODE 2: outf = fp32 row-major [M][1024]
template <int MODE, int BN>
__global__ __launch_bounds__(256) void gemm_kernel(
    const bf16_t* __restrict__ A, const bf16_t* __restrict__ Bt,
    bf16_t* __restrict__ outQ, bf16_t* __restrict__ outK,
    bf16_t* __restrict__ outV, float* __restrict__ outf) {
  constexpr int KD = 1024;
  constexpr int NB = BN / 32;   // B-stage iters per thread
  constexpr int NW = BN / 2;    // wave col span
  constexpr int NACC = NW / 16; // acc cols per wave
  __shared__ bf16_t As[2][128][64];
  __shared__ bf16_t Bs[2][BN][64];
  const int t = threadIdx.x;
  const int lane = t & 63, w = t >> 6;
  const int wr = w >> 1, wc = w & 1;
  const int lrow = lane & 15, lq = lane >> 4;

  // T1 XCD-chunked swizzle (nwg % 8 == 0 for both grids)
  const int nwg = gridDim.x * gridDim.y;
  const int bid = blockIdx.y * gridDim.x + blockIdx.x;
  const int swz = (bid & 7) * (nwg >> 3) + (bid >> 3);
  const int bxs = swz % gridDim.x, bys = swz / gridDim.x;
  const int bm = bys * 128, bn = bxs * BN;

  f32x4 acc[4][NACC] = {};

  auto stage = [&](int buf, int k0) {
    #pragma unroll
    for (int i = 0; i < 4; ++i) {
      const int lin = i * 256 + t;
      const int row = lin >> 3;
      const int sc = (lin & 7) ^ (row & 7);
      gload_lds16(A + (size_t)(bm + row) * KD + k0 + sc * 8,
                  &As[buf][0][0] + lin * 8);
    }
    #pragma unroll
    for (int i = 0; i < NB; ++i) {
      const int lin = i * 256 + t;
      const int row = lin >> 3;
      const int sc = (lin & 7) ^ (row & 7);
      gload_lds16(Bt + (size_t)(bn + row) * KD + k0 + sc * 8,
                  &Bs[buf][0][0] + lin * 8);
    }
  };

  stage(0, 0);
  for (int kt = 0; kt < KD / 64; ++kt) {
    const int cur = kt & 1;
    if (kt + 1 < KD / 64) {
      stage(cur ^ 1, (kt + 1) * 64);
      if constexpr (BN == 128)
        asm volatile("s_waitcnt vmcnt(8)" ::: "memory");
      else
        asm volatile("s_waitcnt vmcnt(6)" ::: "memory");
    } else {
      asm volatile("s_waitcnt vmcnt(0)" ::: "memory");
    }
    __builtin_amdgcn_s_barrier();

    #pragma unroll
    for (int kk = 0; kk < 2; ++kk) {
      bf16x8 aF[4], bF[NACC];
      #pragma unroll
      for (int m = 0; m < 4; ++m) {
        const int row = wr * 64 + m * 16 + lrow;
        const int ch = (kk * 4 + lq) ^ (row & 7);
        aF[m] = *(const bf16x8*)&As[cur][row][ch * 8];
      }
      #pragma unroll
      for (int n = 0; n < NACC; ++n) {
        const int row = wc * NW + n * 16 + lrow;
        const int ch = (kk * 4 + lq) ^ (row & 7);
        bF[n] = *(const bf16x8*)&Bs[cur][row][ch * 8];
      }
      #pragma unroll
      for (int m = 0; m < 4; ++m)
        #pragma unroll
        for (int n = 0; n < NACC; ++n)
          acc[m][n] = __builtin_amdgcn_mfma_f32_16x16x32_bf16(aF[m], bF[n],
                                                              acc[m][n], 0, 0, 0);
    }
    asm volatile("s_waitcnt lgkmcnt(0)" ::: "memory");
    __builtin_amdgcn_s_barrier();
  }

  if constexpr (MODE == 2) {
    #pragma unroll
    for (int m = 0; m < 4; ++m) {
      const int ri = bm + wr * 64 + m * 16 + lq * 4;
      #pragma unroll
      for (int n = 0; n < NACC; ++n) {
        const int ci = bn + wc * NW + n * 16 + lrow;
        const f32x4 v = acc[m][n];
        #pragma unroll
        for (int r = 0; r < 4; ++r)
          outf[(size_t)(ri + r) * 1024 + ci] = v[r];
      }
    }
  } else if (bn < 2048) {
    // ---- Q/K band: LDS-staged frag-major epilogue, coalesced 16B stores ----
    bf16_t* Cs = (bf16_t*)&As[0][0][0];  // 32 KB, exact fit for 128x128 bf16
    bf16_t* dst = (bn < 1024) ? outQ : outK;
    const float sc = (bn < 1024) ? QSCALE : 1.0f;
    #pragma unroll
    for (int m = 0; m < 4; ++m) {
      const int rr0 = wr * 64 + m * 16 + lq * 4;  // relative row (q) base
      #pragma unroll
      for (int n = 0; n < NACC; ++n) {
        const int c = wc * NW + n * 16 + lrow;    // relative col 0..127
        const int hh = c >> 6, d = c & 63;
        const f32x4 v = acc[m][n];
        #pragma unroll
        for (int r = 0; r < 4; ++r) {
          const int rr = rr0 + r;
          const int off = ((hh * 2 + (rr >> 6)) << 12)
                        + (((d >> 4) * 2 + ((rr >> 5) & 1)) << 9)
                        + ((((d >> 3) & 1) * 32 + (rr & 31)) << 3) + (d & 7);
          Cs[off] = (bf16_t)(v[r] * sc);
        }
      }
    }
    __syncthreads();
    const int b = bm >> 11;
    const int qc0 = (bm & 2047) >> 6;
    const int h0 = (bn & 1023) >> 6;
    #pragma unroll
    for (int chk = 0; chk < 4; ++chk) {
      const int hh = chk >> 1, qc = chk & 1;
      bf16_t* gb = dst + (size_t)(b * 16 + h0 + hh) * 131072
                 + (size_t)(qc0 + qc) * 4096;
      #pragma unroll
      for (int it = 0; it < 2; ++it) {
        const int e = (it * 256 + t) * 8;
        *(bf16x8*)(gb + e) = *(const bf16x8*)(Cs + chk * 4096 + e);
      }
    }
  } else {
    // ---- V^T band: frag-major, 4 consecutive j -> 8B vector store ----
    #pragma unroll
    for (int m = 0; m < 4; ++m) {
      const int ri = bm + wr * 64 + m * 16 + lq * 4;
      #pragma unroll
      for (int n = 0; n < NACC; ++n) {
        const int ci = bn + wc * NW + n * 16 + lrow;
        const f32x4 v = acc[m][n];
        const int hd = ci - 2048;
        const int h = hd >> 6, d = hd & 63;
        const int b = ri >> 11, j0 = ri & 2047;
        bf16x4 pk;
        pk[0] = (bf16_t)v[0]; pk[1] = (bf16_t)v[1];
        pk[2] = (bf16_t)v[2]; pk[3] = (bf16_t)v[3];
        const size_t elem = (size_t)(b * 16 + h) * 131072
            + (size_t)((j0 >> 6) * 8 + ((j0 & 63) >> 4) * 2 + (d >> 5)) * 512
            + ((((j0 >> 3) & 1) * 32) + (d & 31)) * 8 + (j0 & 7);
        *(bf16x4*)(outV + elem) = pk;
      }
    }
  }
}

// ---------------- flash attention (strip-paired, proportional wave split) ----
// grid: 1024 blocks x 256 thr (4 waves), all co-resident (4 blocks/CU,
// 4 waves/SIMD at 128-VGPR budget). Logical G = (bid&7)*128 + bid>>3 (XCD
// chunking: 4 bh per XCD -> K/V L2-resident). bh = G>>5, p = G&31.
// Strip A = 63-p (long) gets wA waves (2 or 3, proportional), strip B = p
// gets 4-wA. Per-strip KV-split with stride ws; defer-max; per-lane half-row
// l; permlane32_swap P exchange; per-strip LDS merge, leaders write output.
// NOTE (R12 lesson): do NOT prefetch K across the softmax tail -- the
// register budget is exactly full; extended kc liveness spills to scratch.
__global__ void __attribute__((amdgpu_flat_work_group_size(256, 256),
                               amdgpu_waves_per_eu(4, 4)))
attn_kernel(
    const bf16_t* __restrict__ Qf, const bf16_t* __restrict__ Kf,
    const bf16_t* __restrict__ Vf, bf16_t* __restrict__ Ow) {
  const int t = threadIdx.x;
  const int lane = t & 63, w = t >> 6;
  const int l31 = lane & 31, hi = lane >> 5;
  const int G = ((blockIdx.x & 7) << 7) + (blockIdx.x >> 3);
  const int bh = G >> 5;
  const int p = G & 31;
  const int qsA = 63 - p, qsB = p;
  const int ntA = (qsA >> 1) + 1, ntB = (qsB >> 1) + 1;
  const int wA = min(3, (4 * ntA + ((ntA + ntB) >> 1)) / (ntA + ntB));
  const bool isA = (w < wA);
  const int qs = isA ? qsA : qsB;
  const int nt = isA ? ntA : ntB;
  const int widx = isA ? w : (w - wA);
  const int ws = isA ? wA : (4 - wA);
  const int qg = qs * 32 + l31;               // this lane's q row
  const bf16_t* Qb = Qf + (size_t)bh * 131072 + (size_t)(qs >> 1) * 4096 + (qs & 1) * 512;
  const bf16_t* Kb = Kf + (size_t)bh * 131072;
  const bf16_t* Vb = Vf + (size_t)bh * 131072;

  // Q frags (B-operand): row=q=l31, k = ks*16 + hi*8 + e
  bf16x8 qf[4];
  #pragma unroll
  for (int ks = 0; ks < 4; ++ks)
    qf[ks] = *(const bf16x8*)(Qb + ks * 1024 + lane * 8);

  f32x16 acc0 = {}, acc1 = {};  // O^T: col=q=l31, d = 32*t + 8*(r>>2) + 4*hi + (r&3)
  float m_run = -1e30f, l_half = 0.f;  // l_half: this lane's 32-j partial sum

  for (int jt = widx; jt < nt; jt += ws) {
    const bf16_t* Kt = Kb + (size_t)jt * 4096;
    const bf16_t* Vt = Vb + (size_t)jt * 4096;

    // ---- K frags, coalesced 1KB loads (latency hidden by co-resident waves)
    bf16x8 kc[8];
    #pragma unroll
    for (int f = 0; f < 8; ++f)
      kc[f] = *(const bf16x8*)(Kt + f * 512 + lane * 8);

    // ---- S^T = mfma(K, Q): col=q=l31, j_loc=(r&3)+8*(r>>2)+4hi ----
    f32x16 st0 = {}, st1 = {};
    #pragma unroll
    for (int ks = 0; ks < 4; ++ks) {
      st0 = __builtin_amdgcn_mfma_f32_32x32x16_bf16(kc[2 * ks], qf[ks], st0, 0, 0, 0);
      st1 = __builtin_amdgcn_mfma_f32_32x32x16_bf16(kc[2 * ks + 1], qf[ks], st1, 0, 0, 0);
    }

    // ---- causal mask (only the diagonal tile) ----
    if (jt == nt - 1) {
      const int thr = qg - jt * 64;  // mask where j_loc > thr
      #pragma unroll
      for (int r = 0; r < 16; ++r) {
        const int jl = (r & 3) + 8 * (r >> 2) + 4 * hi;
        st0[r] = (jl > thr) ? -1e30f : st0[r];
        st1[r] = (32 + jl > thr) ? -1e30f : st1[r];
      }
    }

    // ---- per-lane partial max over own 32 values ----
    float t8[8];
    #pragma unroll
    for (int i = 0; i < 8; ++i)
      t8[i] = fmaxf(fmaxf(st0[i], st0[i + 8]), fmaxf(st1[i], st1[i + 8]));
    #pragma unroll
    for (int i = 0; i < 4; ++i) t8[i] = fmaxf(t8[i], t8[i + 4]);
    const float pmax = fmaxf(fmaxf(t8[0], t8[1]), fmaxf(t8[2], t8[3]));

    // ---- defer-max (T13): rescale only when some row grew > threshold ----
    if (!__all(pmax <= m_run + 8.0f)) {
      const float mx = fmaxf(pmax, __shfl_xor(pmax, 32, 64));
      const float m_new = fmaxf(m_run, mx);
      const float corr = fast_exp2(m_run - m_new);
      m_run = m_new;
      l_half *= corr;
      #pragma unroll
      for (int r = 0; r < 16; ++r) { acc0[r] *= corr; acc1[r] *= corr; }
    }

    // ---- exp + per-lane partial sum (no cross-half shuffle) ----
    #pragma unroll
    for (int r = 0; r < 16; ++r) {
      st0[r] = fast_exp2(st0[r] - m_run);
      st1[r] = fast_exp2(st1[r] - m_run);
    }
    float s8[8];
    #pragma unroll
    for (int i = 0; i < 8; ++i)
      s8[i] = (st0[i] + st0[i + 8]) + (st1[i] + st1[i + 8]);
    #pragma unroll
    for (int i = 0; i < 4; ++i) s8[i] += s8[i + 4];
    l_half += (s8[0] + s8[1]) + (s8[2] + s8[3]);

    // ---- V frags issued here (kc/st dying; pack below covers L2 latency) ----
    bf16x8 vf[8];
    #pragma unroll
    for (int f = 0; f < 8; ++f)
      vf[f] = *(const bf16x8*)(Vt + f * 512 + lane * 8);

    // ---- P -> bf16 B-operand frags: pack pairs, permlane32_swap regroup ----
    u32 Wa[8], Wb[8];
    #pragma unroll
    for (int g = 0; g < 8; ++g) {
      Wa[g] = pkbf(st0[2 * g], st0[2 * g + 1]);
      Wb[g] = pkbf(st1[2 * g], st1[2 * g + 1]);
    }
    swap32(Wa[0], Wa[2]); swap32(Wa[1], Wa[3]);
    swap32(Wa[4], Wa[6]); swap32(Wa[5], Wa[7]);
    swap32(Wb[0], Wb[2]); swap32(Wb[1], Wb[3]);
    swap32(Wb[4], Wb[6]); swap32(Wb[5], Wb[7]);
    const uint4 u0 = make_uint4(Wa[0], Wa[1], Wa[2], Wa[3]);
    const uint4 u1 = make_uint4(Wa[4], Wa[5], Wa[6], Wa[7]);
    const uint4 u2 = make_uint4(Wb[0], Wb[1], Wb[2], Wb[3]);
    const uint4 u3 = make_uint4(Wb[4], Wb[5], Wb[6], Wb[7]);
    const bf16x8 pf0 = __builtin_bit_cast(bf16x8, u0);
    const bf16x8 pf1 = __builtin_bit_cast(bf16x8, u1);
    const bf16x8 pf2 = __builtin_bit_cast(bf16x8, u2);
    const bf16x8 pf3 = __builtin_bit_cast(bf16x8, u3);

    // ---- O^T += mfma(V, P) ----
    #pragma unroll
    for (int tt = 0; tt < 4; ++tt) {
      const bf16x8 pf = tt == 0 ? pf0 : tt == 1 ? pf1 : tt == 2 ? pf2 : pf3;
      acc0 = __builtin_amdgcn_mfma_f32_32x32x16_bf16(vf[2 * tt], pf, acc0, 0, 0, 0);
      acc1 = __builtin_amdgcn_mfma_f32_32x32x16_bf16(vf[2 * tt + 1], pf, acc1, 0, 0, 0);
    }
  }

  // ---- combine the two half-lane l partials within the wave ----
  const float l_wave = l_half + __shfl_xor(l_half, 32, 64);

  // ---- cross-wave merge via LDS: per-strip, non-leaders -> leader ----
  __shared__ float mO[2][32][64];
  __shared__ float mML[2][2][64];
  const bool leader = (w == 0) || (w == wA);
  if (!leader) {
    const int slot = isA ? (w - 1) : (wA - 1 + (w - wA - 1));
    mML[0][slot][lane] = m_run;
    mML[1][slot][lane] = l_wave;
    #pragma unroll
    for (int r = 0; r < 16; ++r) {
      mO[slot][r][lane] = acc0[r];
      mO[slot][16 + r][lane] = acc1[r];
    }
  }
  __syncthreads();
  if (leader) {
    const int base = isA ? 0 : (wA - 1);
    const int nsl = ws - 1;  // 0..2 partials to merge
    float mk[2], lk[2], ck[2];
    float mt = m_run;
    for (int k = 0; k < nsl; ++k) {
      mk[k] = mML[0][base + k][lane];
      lk[k] = mML[1][base + k][lane];
      mt = fmaxf(mt, mk[k]);
    }
    const float c0 = fast_exp2(m_run - mt);
    float l = l_wave * c0;
    for (int k = 0; k < nsl; ++k) {
      ck[k] = fast_exp2(mk[k] - mt);
      l += lk[k] * ck[k];
    }
    const float inv = 1.0f / l;
    const int b = bh >> 4, h = bh & 15;
    bf16_t* Obase = Ow + (((size_t)(b * 2048 + qg)) << 10) + h * 64;
    #pragma unroll
    for (int g = 0; g < 4; ++g) {
      bf16x4 p0, p1;
      #pragma unroll
      for (int j = 0; j < 4; ++j) {
        float a0 = acc0[4 * g + j] * c0;
        float a1 = acc1[4 * g + j] * c0;
        for (int k = 0; k < nsl; ++k) {
          a0 += mO[base + k][4 * g + j][lane] * ck[k];
          a1 += mO[base + k][16 + 4 * g + j][lane] * ck[k];
        }
        p0[j] = (bf16_t)(a0 * inv);
        p1[j] = (bf16_t)(a1 * inv);
      }
      *(bf16x4*)(Obase + 8 * g + 4 * hi) = p0;
      *(bf16x4*)(Obase + 32 + 8 * g + 4 * hi) = p1;
    }
  }
}

// ---------------- orchestration ----------------
extern "C" void kernel_launch(void* const* d_in, const int* in_sizes, int n_in,
                              void* d_out, int out_size, void* d_ws, size_t ws_size,
                              hipStream_t stream) {
  const float* x   = (const float*)d_in[0];
  const float* Wq  = (const float*)d_in[1];
  const float* Wkv = (const float*)d_in[2];
  const float* Wo  = (const float*)d_in[3];
  float* out = (float*)d_out;
  char* ws = (char*)d_ws;

  const size_t MB = 1024 * 1024;
  bf16_t* Xbf   = (bf16_t*)(ws);             // [4096][1024]       8 MiB
  bf16_t* Wqkvt = (bf16_t*)(ws + 8 * MB);    // [3072][1024]       6 MiB
  bf16_t* Wot   = (bf16_t*)(ws + 14 * MB);   // [1024][1024]       2 MiB
  bf16_t* Qw    = (bf16_t*)(ws + 16 * MB);   // frag-major Q       8 MiB (pre-scaled)
  bf16_t* Kw    = (bf16_t*)(ws + 24 * MB);   // frag-major K       8 MiB
  bf16_t* Vtw   = (bf16_t*)(ws + 32 * MB);   // frag-major V^T     8 MiB
  bf16_t* Aw    = (bf16_t*)(ws + 40 * MB);   // [4096][1024]       8 MiB

  prep_kernel<<<8192, 256, 0, stream>>>(x, Wq, Wkv, Wo, Xbf, Wqkvt, Wot);
  gemm_kernel<1, 128><<<dim3(24, 32), 256, 0, stream>>>(Xbf, Wqkvt, Qw, Kw, Vtw, nullptr);
  attn_kernel<<<1024, 256, 0, stream>>>(Qw, Kw, Vtw, Aw);
  gemm_kernel<2, 64><<<dim3(16, 32), 256, 0, stream>>>(Aw, Wot, nullptr, nullptr, nullptr, out);
}